// Round 1
// baseline (759.793 us; speedup 1.0000x reference)
//
#include <hip/hip_runtime.h>
#include <hip/hip_bf16.h>
#include <cstdint>

#define VOCAB  50001
#define EMBED  64
#define HIDDEN 100
#define TSTEPS 512
#define BATCH  2048

constexpr int HP_R = 104;   // padded K extent for the h dot-product (mult of 4)
constexpr int HP_A = 128;   // allocated LDS row for h (covers all 128 threads)

// ---------------- Phase 1: P[v][j] = W_ih[j,:]·table[v,:] + b_ih[j] + b_hh[j] ----
__global__ __launch_bounds__(128) void proj_kernel(
    const float* __restrict__ table, const float* __restrict__ Wih,
    const float* __restrict__ bih, const float* __restrict__ bhh,
    float* __restrict__ P)
{
  constexpr int VPB = 16;
  __shared__ float e[VPB][EMBED];
  const int vbase = blockIdx.x * VPB;
  const int tid = threadIdx.x;
  // stage VPB consecutive embedding rows, fully coalesced
  #pragma unroll
  for (int r = 0; r < VPB * EMBED / 128; ++r) {
    const int el = tid + 128 * r;
    const int v  = vbase + (el >> 6);
    e[el >> 6][el & 63] = (v < VOCAB) ? table[(size_t)v * EMBED + (el & 63)] : 0.f;
  }
  __syncthreads();

  const int j = (tid < HIDDEN) ? tid : HIDDEN - 1;
  float w[EMBED];
  #pragma unroll
  for (int k = 0; k < EMBED; k += 4) {
    const float4 t4 = *reinterpret_cast<const float4*>(&Wih[j * EMBED + k]);
    w[k] = t4.x; w[k+1] = t4.y; w[k+2] = t4.z; w[k+3] = t4.w;
  }
  const float bias = bih[j] + bhh[j];

  for (int r = 0; r < VPB; ++r) {
    const int v = vbase + r;
    if (v >= VOCAB) break;
    float acc = bias;
    #pragma unroll
    for (int k = 0; k < EMBED; k += 4) {
      const float4 ev = *reinterpret_cast<const float4*>(&e[r][k]);
      acc += w[k]*ev.x + w[k+1]*ev.y + w[k+2]*ev.z + w[k+3]*ev.w;
    }
    if (tid < HIDDEN) P[(size_t)v * HIDDEN + tid] = acc;
  }
}

// ---------------- Phase 2: per-row recurrence, one block per batch row ----------
template<bool USE_P>
__global__ __launch_bounds__(128, 4) void rnn_kernel(
    const int* __restrict__ x, const float* __restrict__ P,
    const float* __restrict__ table,
    const float* __restrict__ Whh, const float* __restrict__ Wih,
    const float* __restrict__ bih, const float* __restrict__ bhh,
    const float* __restrict__ fcW, const float* __restrict__ fcb,
    float* __restrict__ out)
{
  __shared__ float h_lds[2][HP_A];
  __shared__ float e_lds[2][EMBED];
  __shared__ float red[128];
  const int row = blockIdx.x;
  const int tid = threadIdx.x;
  const int j = (tid < HIDDEN) ? tid : HIDDEN - 1;
  const bool active = tid < HIDDEN;

  // W_hh row j in registers, zero-padded to HP_R
  float w[HP_R];
  #pragma unroll
  for (int k = 0; k < HIDDEN; k += 4) {
    const float4 t4 = *reinterpret_cast<const float4*>(&Whh[j * HIDDEN + k]);
    w[k] = t4.x; w[k+1] = t4.y; w[k+2] = t4.z; w[k+3] = t4.w;
  }
  #pragma unroll
  for (int k = HIDDEN; k < HP_R; ++k) w[k] = 0.f;

  float wi[USE_P ? 4 : EMBED];
  float bias = 0.f;
  if constexpr (!USE_P) {
    #pragma unroll
    for (int k = 0; k < EMBED; k += 4) {
      const float4 t4 = *reinterpret_cast<const float4*>(&Wih[j * EMBED + k]);
      wi[k] = t4.x; wi[k+1] = t4.y; wi[k+2] = t4.z; wi[k+3] = t4.w;
    }
    bias = bih[j] + bhh[j];
  }

  h_lds[0][tid] = 0.f;
  h_lds[1][tid] = 0.f;

  const int* __restrict__ xrow = x + (size_t)row * TSTEPS;
  // prefetch pipeline: i1 = idx for step t+1 (ready), i2 in flight for t+2
  const int i0 = xrow[0];
  float xp_next = 0.f;
  if constexpr (USE_P) {
    xp_next = P[(size_t)i0 * HIDDEN + j];
  } else {
    if (tid < EMBED) e_lds[0][tid] = table[(size_t)i0 * EMBED + tid];
  }
  int i1 = xrow[1];
  __syncthreads();

  float h = 0.f;
  for (int t = 0; t < TSTEPS; ++t) {
    const int cur = t & 1, nxt = cur ^ 1;
    const int i2 = (t + 2 < TSTEPS) ? xrow[t + 2] : 0;   // issue early

    float xp = 0.f;
    if constexpr (USE_P) {
      xp = xp_next;                                       // for this step
      xp_next = P[(size_t)i1 * HIDDEN + j];               // prefetch t+1
    } else {
      if (tid < EMBED) e_lds[nxt][tid] = table[(size_t)i1 * EMBED + tid];
    }

    float acc = bias + xp;
    if constexpr (!USE_P) {
      #pragma unroll
      for (int k = 0; k < EMBED; k += 4) {
        const float4 ev = *reinterpret_cast<const float4*>(&e_lds[cur][k]);
        acc += wi[k]*ev.x + wi[k+1]*ev.y + wi[k+2]*ev.z + wi[k+3]*ev.w;
      }
    }
    #pragma unroll
    for (int k = 0; k < HP_R; k += 4) {
      const float4 hv = *reinterpret_cast<const float4*>(&h_lds[cur][k]);
      acc += w[k]*hv.x + w[k+1]*hv.y + w[k+2]*hv.z + w[k+3]*hv.w;
    }
    h = tanhf(acc);
    h_lds[nxt][tid] = active ? h : 0.f;
    i1 = i2;
    __syncthreads();
  }

  // logits = fc_W · h_final + fc_b ; sigmoid
  red[tid] = active ? h * fcW[j] : 0.f;
  __syncthreads();
  if (tid == 0) {
    float s = fcb[0];
    #pragma unroll
    for (int k = 0; k < HIDDEN; ++k) s += red[k];
    out[row] = 1.f / (1.f + expf(-s));
  }
}

// ---------------- host ----------------------------------------------------------
extern "C" void kernel_launch(void* const* d_in, const int* in_sizes, int n_in,
                              void* d_out, int out_size, void* d_ws, size_t ws_size,
                              hipStream_t stream) {
  const int*   x     = (const int*)  d_in[0];
  const float* table = (const float*)d_in[1];
  const float* Wih   = (const float*)d_in[2];
  const float* Whh   = (const float*)d_in[3];
  const float* bih   = (const float*)d_in[4];
  const float* bhh   = (const float*)d_in[5];
  const float* fcW   = (const float*)d_in[6];
  const float* fcb   = (const float*)d_in[7];
  float* out = (float*)d_out;

  const size_t PROJ_BYTES = (size_t)VOCAB * HIDDEN * sizeof(float);
  if (ws_size >= PROJ_BYTES) {
    float* Pt = (float*)d_ws;
    proj_kernel<<<(VOCAB + 15) / 16, 128, 0, stream>>>(table, Wih, bih, bhh, Pt);
    rnn_kernel<true><<<BATCH, 128, 0, stream>>>(x, Pt, table, Whh, Wih, bih, bhh,
                                                fcW, fcb, out);
  } else {
    rnn_kernel<false><<<BATCH, 128, 0, stream>>>(x, nullptr, table, Whh, Wih, bih,
                                                 bhh, fcW, fcb, out);
  }
}

// Round 2
// 619.428 us; speedup vs baseline: 1.2266x; 1.2266x over previous
//
#include <hip/hip_runtime.h>
#include <hip/hip_bf16.h>
#include <cstdint>

#define VOCAB  50001
#define EMBED  64
#define HIDDEN 100
#define TSTEPS 512
#define BATCH  2048

// ---------------- fast exact tanh: 1 - 2/(1+e^{2x}) --------------------------
__device__ __forceinline__ float fast_tanh(float x) {
  const float e = __expf(2.0f * x);                  // v_mul + v_exp_f32
  return 1.0f - 2.0f * __builtin_amdgcn_rcpf(e + 1.0f);
}

// ---------------- Phase 1: P[v][j] = W_ih[j,:]·table[v,:] + b_ih[j] + b_hh[j] ----
__global__ __launch_bounds__(128) void proj_kernel(
    const float* __restrict__ table, const float* __restrict__ Wih,
    const float* __restrict__ bih, const float* __restrict__ bhh,
    float* __restrict__ P)
{
  constexpr int VPB = 16;
  __shared__ float e[VPB][EMBED];
  const int vbase = blockIdx.x * VPB;
  const int tid = threadIdx.x;
  #pragma unroll
  for (int r = 0; r < VPB * EMBED / 128; ++r) {
    const int el = tid + 128 * r;
    const int v  = vbase + (el >> 6);
    e[el >> 6][el & 63] = (v < VOCAB) ? table[(size_t)v * EMBED + (el & 63)] : 0.f;
  }
  __syncthreads();

  const int j = (tid < HIDDEN) ? tid : HIDDEN - 1;
  float w[EMBED];
  #pragma unroll
  for (int k = 0; k < EMBED; k += 4) {
    const float4 t4 = *reinterpret_cast<const float4*>(&Wih[j * EMBED + k]);
    w[k] = t4.x; w[k+1] = t4.y; w[k+2] = t4.z; w[k+3] = t4.w;
  }
  const float bias = bih[j] + bhh[j];

  for (int r = 0; r < VPB; ++r) {
    const int v = vbase + r;
    if (v >= VOCAB) break;
    float acc = bias;
    #pragma unroll
    for (int k = 0; k < EMBED; k += 4) {
      const float4 ev = *reinterpret_cast<const float4*>(&e[r][k]);
      acc += w[k]*ev.x + w[k+1]*ev.y + w[k+2]*ev.z + w[k+3]*ev.w;
    }
    if (tid < HIDDEN) P[(size_t)v * HIDDEN + tid] = acc;
  }
}

// ---------------- Phase 2: one WAVE per batch row, barrier-free ----------------
// lane l owns hidden units u0 = l (always) and u1 = 64+l (valid for l < 36).
// Both units share the same broadcast h reads: 25 ds_read_b128 -> 200 FMAs.
__global__ __launch_bounds__(64, 2) void rnn_wave_kernel(
    const int* __restrict__ x, const float* __restrict__ P,
    const float* __restrict__ Whh,
    const float* __restrict__ fcW, const float* __restrict__ fcb,
    float* __restrict__ out)
{
  __shared__ float h_lds[2][112];
  const int row = blockIdx.x;
  const int l = threadIdx.x;            // 0..63
  const int u0 = l;
  const bool m1 = (l < HIDDEN - 64);    // l < 36
  const int u1 = m1 ? (64 + l) : (HIDDEN - 1);

  // W_hh rows for both units, fully register-resident (200 VGPRs).
  float w0[HIDDEN], w1[HIDDEN];
  #pragma unroll
  for (int k = 0; k < HIDDEN; k += 4) {
    const float4 a = *reinterpret_cast<const float4*>(&Whh[u0 * HIDDEN + k]);
    w0[k] = a.x; w0[k+1] = a.y; w0[k+2] = a.z; w0[k+3] = a.w;
    const float4 b = *reinterpret_cast<const float4*>(&Whh[u1 * HIDDEN + k]);
    w1[k] = b.x; w1[k+1] = b.y; w1[k+2] = b.z; w1[k+3] = b.w;
  }

  // zero initial h buffer (buffer 0 only; buffer 1 fully written before read)
  h_lds[0][l] = 0.f;
  h_lds[0][l + 48] = 0.f;

  const int* __restrict__ xrow = x + (size_t)row * TSTEPS;
  // xp prefetch pipeline: xp for step t ready; idx for t+1 in i_nx.
  const int i0 = xrow[0];
  float xp0 = P[i0 * HIDDEN + u0];
  float xp1 = P[i0 * HIDDEN + u1];
  int i_nx = xrow[1];

  float h0 = 0.f, h1 = 0.f;
  for (int t = 0; t < TSTEPS; ++t) {
    const int cur = t & 1, nxt = cur ^ 1;
    // prefetch xp for t+1 (tail reads P row 0 -- harmless)
    const float xp0n = P[i_nx * HIDDEN + u0];
    const float xp1n = P[i_nx * HIDDEN + u1];
    i_nx = (t + 2 < TSTEPS) ? xrow[t + 2] : 0;

    float acc0 = xp0, acc1 = xp1;
    const float* hb = &h_lds[cur][0];
    #pragma unroll
    for (int k = 0; k < HIDDEN; k += 4) {
      const float4 hv = *reinterpret_cast<const float4*>(&hb[k]);
      acc0 += w0[k]*hv.x + w0[k+1]*hv.y + w0[k+2]*hv.z + w0[k+3]*hv.w;
      acc1 += w1[k]*hv.x + w1[k+1]*hv.y + w1[k+2]*hv.z + w1[k+3]*hv.w;
    }
    h0 = fast_tanh(acc0);
    h1 = fast_tanh(acc1);
    h_lds[nxt][u0] = h0;
    if (m1) h_lds[nxt][u1] = h1;
    xp0 = xp0n; xp1 = xp1n;
  }

  // FC + sigmoid: wave reduction
  float s = h0 * fcW[u0] + (m1 ? h1 * fcW[u1] : 0.f);
  #pragma unroll
  for (int off = 32; off > 0; off >>= 1) s += __shfl_down(s, off);
  if (l == 0) out[row] = 1.0f / (1.0f + __expf(-(s + fcb[0])));
}

// ---------------- fallback (no workspace): original 128-thread version ---------
__global__ __launch_bounds__(128, 2) void rnn_fallback_kernel(
    const int* __restrict__ x, const float* __restrict__ table,
    const float* __restrict__ Whh, const float* __restrict__ Wih,
    const float* __restrict__ bih, const float* __restrict__ bhh,
    const float* __restrict__ fcW, const float* __restrict__ fcb,
    float* __restrict__ out)
{
  __shared__ float h_lds[2][128];
  __shared__ float e_lds[2][EMBED];
  __shared__ float red[128];
  const int row = blockIdx.x;
  const int tid = threadIdx.x;
  const int j = (tid < HIDDEN) ? tid : HIDDEN - 1;
  const bool active = tid < HIDDEN;

  float w[HIDDEN];
  #pragma unroll
  for (int k = 0; k < HIDDEN; k += 4) {
    const float4 t4 = *reinterpret_cast<const float4*>(&Whh[j * HIDDEN + k]);
    w[k] = t4.x; w[k+1] = t4.y; w[k+2] = t4.z; w[k+3] = t4.w;
  }
  float wi[EMBED];
  #pragma unroll
  for (int k = 0; k < EMBED; k += 4) {
    const float4 t4 = *reinterpret_cast<const float4*>(&Wih[j * EMBED + k]);
    wi[k] = t4.x; wi[k+1] = t4.y; wi[k+2] = t4.z; wi[k+3] = t4.w;
  }
  const float bias = bih[j] + bhh[j];

  h_lds[0][tid] = 0.f;
  const int* __restrict__ xrow = x + (size_t)row * TSTEPS;
  const int i0 = xrow[0];
  if (tid < EMBED) e_lds[0][tid] = table[(size_t)i0 * EMBED + tid];
  int i1 = xrow[1];
  __syncthreads();

  float h = 0.f;
  for (int t = 0; t < TSTEPS; ++t) {
    const int cur = t & 1, nxt = cur ^ 1;
    const int i2 = (t + 2 < TSTEPS) ? xrow[t + 2] : 0;
    if (tid < EMBED) e_lds[nxt][tid] = table[(size_t)i1 * EMBED + tid];

    float acc = bias;
    #pragma unroll
    for (int k = 0; k < EMBED; k += 4) {
      const float4 ev = *reinterpret_cast<const float4*>(&e_lds[cur][k]);
      acc += wi[k]*ev.x + wi[k+1]*ev.y + wi[k+2]*ev.z + wi[k+3]*ev.w;
    }
    #pragma unroll
    for (int k = 0; k < HIDDEN; k += 4) {
      const float4 hv = *reinterpret_cast<const float4*>(&h_lds[cur][k]);
      acc += w[k]*hv.x + w[k+1]*hv.y + w[k+2]*hv.z + w[k+3]*hv.w;
    }
    h = fast_tanh(acc);
    h_lds[nxt][tid] = active ? h : 0.f;
    i1 = i2;
    __syncthreads();
  }

  red[tid] = active ? h * fcW[j] : 0.f;
  __syncthreads();
  if (tid == 0) {
    float s = fcb[0];
    #pragma unroll
    for (int k = 0; k < HIDDEN; ++k) s += red[k];
    out[row] = 1.0f / (1.0f + __expf(-s));
  }
}

// ---------------- host ----------------------------------------------------------
extern "C" void kernel_launch(void* const* d_in, const int* in_sizes, int n_in,
                              void* d_out, int out_size, void* d_ws, size_t ws_size,
                              hipStream_t stream) {
  const int*   x     = (const int*)  d_in[0];
  const float* table = (const float*)d_in[1];
  const float* Wih   = (const float*)d_in[2];
  const float* Whh   = (const float*)d_in[3];
  const float* bih   = (const float*)d_in[4];
  const float* bhh   = (const float*)d_in[5];
  const float* fcW   = (const float*)d_in[6];
  const float* fcb   = (const float*)d_in[7];
  float* out = (float*)d_out;

  const size_t PROJ_BYTES = (size_t)VOCAB * HIDDEN * sizeof(float);
  if (ws_size >= PROJ_BYTES) {
    float* Pt = (float*)d_ws;
    proj_kernel<<<(VOCAB + 15) / 16, 128, 0, stream>>>(table, Wih, bih, bhh, Pt);
    rnn_wave_kernel<<<BATCH, 64, 0, stream>>>(x, Pt, Whh, fcW, fcb, out);
  } else {
    rnn_fallback_kernel<<<BATCH, 128, 0, stream>>>(x, table, Whh, Wih, bih, bhh,
                                                   fcW, fcb, out);
  }
}

// Round 3
// 587.972 us; speedup vs baseline: 1.2922x; 1.0535x over previous
//
#include <hip/hip_runtime.h>
#include <hip/hip_bf16.h>
#include <cstdint>

#define VOCAB  50001
#define EMBED  64
#define HIDDEN 100
#define TSTEPS 512
#define BATCH  2048

// ---------------- fast exact-limit tanh: 1 - 2/(1+e^{2x}) --------------------
__device__ __forceinline__ float fast_tanh(float x) {
  const float e = __expf(2.0f * x);
  return 1.0f - 2.0f * __builtin_amdgcn_rcpf(e + 1.0f);
}

// ---------------- Phase 1: P[v][j] = W_ih[j,:]·table[v,:] + b_ih[j] + b_hh[j] ----
__global__ __launch_bounds__(128) void proj_kernel(
    const float* __restrict__ table, const float* __restrict__ Wih,
    const float* __restrict__ bih, const float* __restrict__ bhh,
    float* __restrict__ P)
{
  constexpr int VPB = 16;
  __shared__ float e[VPB][EMBED];
  const int vbase = blockIdx.x * VPB;
  const int tid = threadIdx.x;
  #pragma unroll
  for (int r = 0; r < VPB * EMBED / 128; ++r) {
    const int el = tid + 128 * r;
    const int v  = vbase + (el >> 6);
    e[el >> 6][el & 63] = (v < VOCAB) ? table[(size_t)v * EMBED + (el & 63)] : 0.f;
  }
  __syncthreads();

  const int j = (tid < HIDDEN) ? tid : HIDDEN - 1;
  float w[EMBED];
  #pragma unroll
  for (int k = 0; k < EMBED; k += 4) {
    const float4 t4 = *reinterpret_cast<const float4*>(&Wih[j * EMBED + k]);
    w[k] = t4.x; w[k+1] = t4.y; w[k+2] = t4.z; w[k+3] = t4.w;
  }
  const float bias = bih[j] + bhh[j];

  for (int r = 0; r < VPB; ++r) {
    const int v = vbase + r;
    if (v >= VOCAB) break;
    float acc = bias;
    #pragma unroll
    for (int k = 0; k < EMBED; k += 4) {
      const float4 ev = *reinterpret_cast<const float4*>(&e[r][k]);
      acc += w[k]*ev.x + w[k+1]*ev.y + w[k+2]*ev.z + w[k+3]*ev.w;
    }
    if (tid < HIDDEN) P[(size_t)v * HIDDEN + tid] = acc;
  }
}

// ---------------- Phase 2: one WAVE per batch row, barrier-free ----------------
// lane l owns units u0=l and u1=64+l (l<36). Weights for both units pinned in
// VGPRs: amdgpu_waves_per_eu(2,2) clamps occupancy to exactly 2 waves/EU
// (VGPR budget 256) so the allocator stops rematerializing the Whh loads.
__global__ __launch_bounds__(64)
__attribute__((amdgpu_waves_per_eu(2, 2)))
void rnn_wave_kernel(
    const int* __restrict__ x, const float* __restrict__ P,
    const float* __restrict__ Whh,
    const float* __restrict__ fcW, const float* __restrict__ fcb,
    float* __restrict__ out)
{
  __shared__ float h_lds[2][112];
  const int row = blockIdx.x;
  const int l = threadIdx.x;            // 0..63
  const int u0 = l;
  const bool m1 = (l < HIDDEN - 64);    // l < 36
  const int u1 = m1 ? (64 + l) : (HIDDEN - 1);

  // W_hh rows for both units -> 200 VGPRs, genuinely register-resident.
  float w0[HIDDEN], w1[HIDDEN];
  #pragma unroll
  for (int k = 0; k < HIDDEN; k += 4) {
    const float4 a = *reinterpret_cast<const float4*>(&Whh[u0 * HIDDEN + k]);
    w0[k] = a.x; w0[k+1] = a.y; w0[k+2] = a.z; w0[k+3] = a.w;
    const float4 b = *reinterpret_cast<const float4*>(&Whh[u1 * HIDDEN + k]);
    w1[k] = b.x; w1[k+1] = b.y; w1[k+2] = b.z; w1[k+3] = b.w;
  }
  const float fw0 = fcW[u0];
  const float fw1 = m1 ? fcW[u1] : 0.f;

  h_lds[0][l] = 0.f;
  h_lds[0][l + 48] = 0.f;

  const int* __restrict__ xrow = x + (size_t)row * TSTEPS;
  const int i0 = xrow[0];
  float xp0 = P[i0 * HIDDEN + u0];
  float xp1 = P[i0 * HIDDEN + u1];
  int i_nx = xrow[1];

  float h0 = 0.f, h1 = 0.f;
  for (int t = 0; t < TSTEPS; ++t) {
    const int cur = t & 1, nxt = cur ^ 1;
    // prefetch xp for t+1 (tail reads P row 0 -- harmless)
    const float* __restrict__ Prow = P + i_nx * HIDDEN;
    const float xp0n = Prow[u0];
    const float xp1n = Prow[u1];
    i_nx = (t + 2 < TSTEPS) ? xrow[t + 2] : 0;

    // two interleaved accumulators per unit: halve the serial FMA chain
    float a0 = xp0, b0 = 0.f, a1 = xp1, b1 = 0.f;
    const float4* __restrict__ hb =
        reinterpret_cast<const float4*>(&h_lds[cur][0]);
    #pragma unroll
    for (int g = 0; g < HIDDEN / 4; ++g) {
      const float4 hv = hb[g];
      const int k = 4 * g;
      if ((g & 1) == 0) {
        a0 += w0[k]*hv.x + w0[k+1]*hv.y + w0[k+2]*hv.z + w0[k+3]*hv.w;
        a1 += w1[k]*hv.x + w1[k+1]*hv.y + w1[k+2]*hv.z + w1[k+3]*hv.w;
      } else {
        b0 += w0[k]*hv.x + w0[k+1]*hv.y + w0[k+2]*hv.z + w0[k+3]*hv.w;
        b1 += w1[k]*hv.x + w1[k+1]*hv.y + w1[k+2]*hv.z + w1[k+3]*hv.w;
      }
    }
    h0 = fast_tanh(a0 + b0);
    h1 = fast_tanh(a1 + b1);
    h_lds[nxt][u0] = h0;
    if (m1) h_lds[nxt][u1] = h1;
    xp0 = xp0n; xp1 = xp1n;
  }

  // FC + sigmoid: wave reduction
  float s = h0 * fw0 + (m1 ? h1 * fw1 : 0.f);
  #pragma unroll
  for (int off = 32; off > 0; off >>= 1) s += __shfl_down(s, off);
  if (l == 0) out[row] = 1.0f / (1.0f + __expf(-(s + fcb[0])));
}

// ---------------- fallback (no workspace) --------------------------------------
__global__ __launch_bounds__(128, 2) void rnn_fallback_kernel(
    const int* __restrict__ x, const float* __restrict__ table,
    const float* __restrict__ Whh, const float* __restrict__ Wih,
    const float* __restrict__ bih, const float* __restrict__ bhh,
    const float* __restrict__ fcW, const float* __restrict__ fcb,
    float* __restrict__ out)
{
  __shared__ float h_lds[2][128];
  __shared__ float e_lds[2][EMBED];
  __shared__ float red[128];
  const int row = blockIdx.x;
  const int tid = threadIdx.x;
  const int j = (tid < HIDDEN) ? tid : HIDDEN - 1;
  const bool active = tid < HIDDEN;

  float w[HIDDEN];
  #pragma unroll
  for (int k = 0; k < HIDDEN; k += 4) {
    const float4 t4 = *reinterpret_cast<const float4*>(&Whh[j * HIDDEN + k]);
    w[k] = t4.x; w[k+1] = t4.y; w[k+2] = t4.z; w[k+3] = t4.w;
  }
  float wi[EMBED];
  #pragma unroll
  for (int k = 0; k < EMBED; k += 4) {
    const float4 t4 = *reinterpret_cast<const float4*>(&Wih[j * EMBED + k]);
    wi[k] = t4.x; wi[k+1] = t4.y; wi[k+2] = t4.z; wi[k+3] = t4.w;
  }
  const float bias = bih[j] + bhh[j];

  h_lds[0][tid] = 0.f;
  const int* __restrict__ xrow = x + (size_t)row * TSTEPS;
  const int i0 = xrow[0];
  if (tid < EMBED) e_lds[0][tid] = table[(size_t)i0 * EMBED + tid];
  int i1 = xrow[1];
  __syncthreads();

  float h = 0.f;
  for (int t = 0; t < TSTEPS; ++t) {
    const int cur = t & 1, nxt = cur ^ 1;
    const int i2 = (t + 2 < TSTEPS) ? xrow[t + 2] : 0;
    if (tid < EMBED) e_lds[nxt][tid] = table[(size_t)i1 * EMBED + tid];

    float acc = bias;
    #pragma unroll
    for (int k = 0; k < EMBED; k += 4) {
      const float4 ev = *reinterpret_cast<const float4*>(&e_lds[cur][k]);
      acc += wi[k]*ev.x + wi[k+1]*ev.y + wi[k+2]*ev.z + wi[k+3]*ev.w;
    }
    #pragma unroll
    for (int k = 0; k < HIDDEN; k += 4) {
      const float4 hv = *reinterpret_cast<const float4*>(&h_lds[cur][k]);
      acc += w[k]*hv.x + w[k+1]*hv.y + w[k+2]*hv.z + w[k+3]*hv.w;
    }
    h = fast_tanh(acc);
    h_lds[nxt][tid] = active ? h : 0.f;
    i1 = i2;
    __syncthreads();
  }

  red[tid] = active ? h * fcW[j] : 0.f;
  __syncthreads();
  if (tid == 0) {
    float s = fcb[0];
    #pragma unroll
    for (int k = 0; k < HIDDEN; ++k) s += red[k];
    out[row] = 1.0f / (1.0f + __expf(-s));
  }
}

// ---------------- host ----------------------------------------------------------
extern "C" void kernel_launch(void* const* d_in, const int* in_sizes, int n_in,
                              void* d_out, int out_size, void* d_ws, size_t ws_size,
                              hipStream_t stream) {
  const int*   x     = (const int*)  d_in[0];
  const float* table = (const float*)d_in[1];
  const float* Wih   = (const float*)d_in[2];
  const float* Whh   = (const float*)d_in[3];
  const float* bih   = (const float*)d_in[4];
  const float* bhh   = (const float*)d_in[5];
  const float* fcW   = (const float*)d_in[6];
  const float* fcb   = (const float*)d_in[7];
  float* out = (float*)d_out;

  const size_t PROJ_BYTES = (size_t)VOCAB * HIDDEN * sizeof(float);
  if (ws_size >= PROJ_BYTES) {
    float* Pt = (float*)d_ws;
    proj_kernel<<<(VOCAB + 15) / 16, 128, 0, stream>>>(table, Wih, bih, bhh, Pt);
    rnn_wave_kernel<<<BATCH, 64, 0, stream>>>(x, Pt, Whh, fcW, fcb, out);
  } else {
    rnn_fallback_kernel<<<BATCH, 128, 0, stream>>>(x, table, Whh, Wih, bih, bhh,
                                                   fcW, fcb, out);
  }
}

// Round 4
// 418.818 us; speedup vs baseline: 1.8141x; 1.4039x over previous
//
#include <hip/hip_runtime.h>
#include <hip/hip_bf16.h>
#include <cstdint>

#define VOCAB  50001
#define EMBED  64
#define HIDDEN 100
#define TSTEPS 512
#define BATCH  2048

typedef short bf16x8 __attribute__((ext_vector_type(8)));
typedef float f32x4  __attribute__((ext_vector_type(4)));

constexpr int RB = 16;               // batch rows per block
constexpr int KP = 128;              // padded K (hidden) for MFMA
constexpr int UP = 112;              // padded units (M)
constexpr int NBLK = BATCH / RB;     // 128 blocks

constexpr size_t WHH_BYTES = (size_t)UP * KP * 2;      // 28672 per half
constexpr size_t P_OFF     = 2 * WHH_BYTES;            // 57344
constexpr size_t P_BYTES   = (size_t)VOCAB * HIDDEN * 4;
constexpr size_t WS_NEED   = P_OFF + P_BYTES;

__device__ __forceinline__ float fast_tanh(float x) {
  const float e = __expf(2.0f * x);
  return 1.0f - 2.0f * __builtin_amdgcn_rcpf(e + 1.0f);
}
__device__ __forceinline__ unsigned cvt_pk_bf16(float a, float b) {
  unsigned r;
  asm("v_cvt_pk_bf16_f32 %0, %1, %2" : "=v"(r) : "v"(a), "v"(b));
  return r;
}
__device__ __forceinline__ f32x4 zf4() { f32x4 z = {0.f, 0.f, 0.f, 0.f}; return z; }

#define MFMA16(A,B,C) __builtin_amdgcn_mfma_f32_16x16x32_bf16((A),(B),(C),0,0,0)

// ---------------- P[v][j] = W_ih[j,:]·table[v,:] + b_ih[j] + b_hh[j] -----------
__global__ __launch_bounds__(128) void proj_kernel(
    const float* __restrict__ table, const float* __restrict__ Wih,
    const float* __restrict__ bih, const float* __restrict__ bhh,
    float* __restrict__ P)
{
  constexpr int VPB = 16;
  __shared__ float e[VPB][EMBED];
  const int vbase = blockIdx.x * VPB;
  const int tid = threadIdx.x;
  #pragma unroll
  for (int r = 0; r < VPB * EMBED / 128; ++r) {
    const int el = tid + 128 * r;
    const int v  = vbase + (el >> 6);
    e[el >> 6][el & 63] = (v < VOCAB) ? table[(size_t)v * EMBED + (el & 63)] : 0.f;
  }
  __syncthreads();

  const int j = (tid < HIDDEN) ? tid : HIDDEN - 1;
  float w[EMBED];
  #pragma unroll
  for (int k = 0; k < EMBED; k += 4) {
    const float4 t4 = *reinterpret_cast<const float4*>(&Wih[j * EMBED + k]);
    w[k] = t4.x; w[k+1] = t4.y; w[k+2] = t4.z; w[k+3] = t4.w;
  }
  const float bias = bih[j] + bhh[j];

  for (int r = 0; r < VPB; ++r) {
    const int v = vbase + r;
    if (v >= VOCAB) break;
    float acc = bias;
    #pragma unroll
    for (int k = 0; k < EMBED; k += 4) {
      const float4 ev = *reinterpret_cast<const float4*>(&e[r][k]);
      acc += w[k]*ev.x + w[k+1]*ev.y + w[k+2]*ev.z + w[k+3]*ev.w;
    }
    if (tid < HIDDEN) P[(size_t)v * HIDDEN + tid] = acc;
  }
}

// ---------------- Whh -> split-bf16 padded [UP][KP] (hi, lo) -------------------
__global__ __launch_bounds__(256) void prep_whh(
    const float* __restrict__ Whh, unsigned short* __restrict__ hi,
    unsigned short* __restrict__ lo)
{
  const int i = blockIdx.x * 256 + threadIdx.x;
  if (i >= UP * KP) return;
  const int u = i >> 7, k = i & (KP - 1);
  const float v = (u < HIDDEN && k < HIDDEN) ? Whh[u * HIDDEN + k] : 0.f;
  const unsigned b = __float_as_uint(v);
  const unsigned h16 = (b + 0x7FFFu + ((b >> 16) & 1u)) >> 16;
  const float hf = __uint_as_float(h16 << 16);
  const float r = v - hf;
  const unsigned rb = __float_as_uint(r);
  const unsigned l16 = (rb + 0x7FFFu + ((rb >> 16) & 1u)) >> 16;
  hi[i] = (unsigned short)h16;
  lo[i] = (unsigned short)l16;
}

// ---------------- MFMA recurrence: 16 rows/block, 4 waves ----------------------
// G^T[UP][16] = WhhP[UP][KP] x hT[KP][16]  per step; D frag: unit=(l>>4)*4+r+16*mt,
// row=l&15. A frag: unit=mt*16+(l&15), k-consecutive. B frag: h[row=l&15][k-consec].
__global__ __launch_bounds__(256, 1)
void rnn_mfma_kernel(const int* __restrict__ x, const unsigned char* __restrict__ ws,
                     const float* __restrict__ fcW, const float* __restrict__ fcb,
                     float* __restrict__ out)
{
  __shared__ __align__(16) unsigned char hbuf[2][2][4096]; // [buf][hi/lo][16 rows][128 k] bf16
  __shared__ int idx_lds[TSTEPS][RB];
  __shared__ float red[64];

  const int tid = threadIdx.x;
  const int w   = tid >> 6;
  const int l   = tid & 63;
  const int row = l & 15;
  const int g   = l >> 4;
  const int row0 = blockIdx.x * RB;
  const unsigned swz = (unsigned)((row & 7) << 4);

  // zero h buffers (doubles as h0 = 0)
  {
    uint4* hz = reinterpret_cast<uint4*>(&hbuf[0][0][0]);
    #pragma unroll
    for (int i = 0; i < 4; ++i) hz[tid + 256 * i] = make_uint4(0u, 0u, 0u, 0u);
  }
  // stage x indices transposed: idx_lds[t][r]
  {
    const int r = tid >> 4, tl = tid & 15;
    const int* __restrict__ xr = x + (size_t)(row0 + r) * TSTEPS;
    for (int c = 0; c < TSTEPS / 16; ++c) {
      const int t = tl + 16 * c;
      idx_lds[t][r] = xr[t];
    }
  }

  const unsigned char* __restrict__ WH = ws;
  const unsigned char* __restrict__ WL = ws + WHH_BYTES;
  const float* __restrict__ Pb = reinterpret_cast<const float*>(ws + P_OFF);

  const int  mt0  = w;
  const bool has2 = (w < 3);
  const int  mt1  = has2 ? (w + 4) : 0;

  // loop-invariant A fragments in registers (Whh split)
  bf16x8 whi0[4], wlo0[4], whi1[4], wlo1[4];
  #pragma unroll
  for (int kt = 0; kt < 4; ++kt) {
    const unsigned off0 = (unsigned)(mt0 * 16 + row) * 256u + (unsigned)(kt * 64 + g * 16);
    whi0[kt] = *reinterpret_cast<const bf16x8*>(WH + off0);
    wlo0[kt] = *reinterpret_cast<const bf16x8*>(WL + off0);
    const unsigned off1 = (unsigned)(mt1 * 16 + row) * 256u + (unsigned)(kt * 64 + g * 16);
    whi1[kt] = *reinterpret_cast<const bf16x8*>(WH + off1);
    wlo1[kt] = *reinterpret_cast<const bf16x8*>(WL + off1);
  }

  const int  useed0 = mt0 * 16 + g * 4;          // <= 60, always valid
  const int  useed1 = mt1 * 16 + g * 4;
  const bool ok1 = has2 && (useed1 <= 96);       // mt=6,g>0 are pure padding

  __syncthreads();

  // seed prefetch (depth 2): SA for even steps, SB for odd
  f32x4 SA[2], SB[2];
  {
    const int x0 = idx_lds[0][row];
    const int x1 = idx_lds[1][row];
    SA[0] = *reinterpret_cast<const f32x4*>(Pb + (size_t)x0 * HIDDEN + useed0);
    SB[0] = *reinterpret_cast<const f32x4*>(Pb + (size_t)x1 * HIDDEN + useed0);
    SA[1] = ok1 ? *reinterpret_cast<const f32x4*>(Pb + (size_t)x0 * HIDDEN + useed1) : zf4();
    SB[1] = ok1 ? *reinterpret_cast<const f32x4*>(Pb + (size_t)x1 * HIDDEN + useed1) : zf4();
  }

  auto body = [&](int t, const unsigned char* hbR, unsigned char* hbW, f32x4 (&S)[2]) {
    // B fragments (h hi/lo), XOR-swizzled rows -> 2-way conflicts only
    bf16x8 bhi[4], blo[4];
    #pragma unroll
    for (int kt = 0; kt < 4; ++kt) {
      const unsigned off = ((unsigned)(row * 256 + kt * 64 + g * 16)) ^ swz;
      bhi[kt] = *reinterpret_cast<const bf16x8*>(hbR + off);
      blo[kt] = *reinterpret_cast<const bf16x8*>(hbR + 4096 + off);
    }
    // tile 0: 3 split products on independent accumulators
    f32x4 a1 = S[0], a2 = zf4(), a3 = zf4();
    #pragma unroll
    for (int kt = 0; kt < 4; ++kt) {
      a1 = MFMA16(whi0[kt], bhi[kt], a1);
      a2 = MFMA16(whi0[kt], blo[kt], a2);
      a3 = MFMA16(wlo0[kt], bhi[kt], a3);
    }
    const f32x4 d0 = (a1 + a2) + a3;
    f32x4 d1 = zf4();
    if (has2) {
      f32x4 c1 = S[1], c2 = zf4(), c3 = zf4();
      #pragma unroll
      for (int kt = 0; kt < 4; ++kt) {
        c1 = MFMA16(whi1[kt], bhi[kt], c1);
        c2 = MFMA16(whi1[kt], blo[kt], c2);
        c3 = MFMA16(wlo1[kt], bhi[kt], c3);
      }
      d1 = (c1 + c2) + c3;
    }
    // refill seeds for t+2 (2-step prefetch hides L3/HBM gather latency)
    {
      const int tn = (t + 2 < TSTEPS) ? t + 2 : TSTEPS - 1;
      const int xt = idx_lds[tn][row];
      S[0] = *reinterpret_cast<const f32x4*>(Pb + (size_t)xt * HIDDEN + useed0);
      if (ok1) S[1] = *reinterpret_cast<const f32x4*>(Pb + (size_t)xt * HIDDEN + useed1);
    }
    // tanh -> split bf16 -> LDS (tile 0)
    {
      const float t0 = fast_tanh(d0[0]), t1v = fast_tanh(d0[1]);
      const float t2 = fast_tanh(d0[2]), t3v = fast_tanh(d0[3]);
      const unsigned ph01 = cvt_pk_bf16(t0, t1v), ph23 = cvt_pk_bf16(t2, t3v);
      const float h0f = __uint_as_float(ph01 << 16), h1f = __uint_as_float(ph01 & 0xFFFF0000u);
      const float h2f = __uint_as_float(ph23 << 16), h3f = __uint_as_float(ph23 & 0xFFFF0000u);
      const unsigned pl01 = cvt_pk_bf16(t0 - h0f, t1v - h1f);
      const unsigned pl23 = cvt_pk_bf16(t2 - h2f, t3v - h3f);
      const unsigned off = ((unsigned)(row * 256 + useed0 * 2)) ^ swz;
      *reinterpret_cast<uint2*>(hbW + off)        = make_uint2(ph01, ph23);
      *reinterpret_cast<uint2*>(hbW + 4096 + off) = make_uint2(pl01, pl23);
    }
    if (ok1) {
      const float t0 = fast_tanh(d1[0]), t1v = fast_tanh(d1[1]);
      const float t2 = fast_tanh(d1[2]), t3v = fast_tanh(d1[3]);
      const unsigned ph01 = cvt_pk_bf16(t0, t1v), ph23 = cvt_pk_bf16(t2, t3v);
      const float h0f = __uint_as_float(ph01 << 16), h1f = __uint_as_float(ph01 & 0xFFFF0000u);
      const float h2f = __uint_as_float(ph23 << 16), h3f = __uint_as_float(ph23 & 0xFFFF0000u);
      const unsigned pl01 = cvt_pk_bf16(t0 - h0f, t1v - h1f);
      const unsigned pl23 = cvt_pk_bf16(t2 - h2f, t3v - h3f);
      const unsigned off = ((unsigned)(row * 256 + useed1 * 2)) ^ swz;
      *reinterpret_cast<uint2*>(hbW + off)        = make_uint2(ph01, ph23);
      *reinterpret_cast<uint2*>(hbW + 4096 + off) = make_uint2(pl01, pl23);
    }
    __syncthreads();
  };

  for (int t = 0; t < TSTEPS; t += 2) {
    body(t,     &hbuf[0][0][0], &hbuf[1][0][0], SA);
    body(t + 1, &hbuf[1][0][0], &hbuf[0][0][0], SB);
  }

  // FC + sigmoid (final h is in hbuf[0])
  if (w == 0) {
    const unsigned char* hbF  = &hbuf[0][0][0];
    const unsigned char* hbFl = &hbuf[0][1][0];
    float part = 0.f;
    for (int i = 0; i < 25; ++i) {
      const int u = g * 25 + i;
      const unsigned off = ((unsigned)(row * 256 + u * 2)) ^ swz;
      const unsigned short vh = *reinterpret_cast<const unsigned short*>(hbF + off);
      const unsigned short vl = *reinterpret_cast<const unsigned short*>(hbFl + off);
      const float hv = __uint_as_float((unsigned)vh << 16) +
                       __uint_as_float((unsigned)vl << 16);
      part += hv * fcW[u];
    }
    red[l] = part;
  }
  __syncthreads();
  if (tid < RB) {
    const float s = red[tid] + red[tid + 16] + red[tid + 32] + red[tid + 48] + fcb[0];
    out[row0 + tid] = 1.0f / (1.0f + __expf(-s));
  }
}

// ---------------- fallback: previous exact fp32 wave kernel --------------------
__global__ __launch_bounds__(64)
__attribute__((amdgpu_waves_per_eu(2, 2)))
void rnn_wave_kernel(
    const int* __restrict__ x, const float* __restrict__ P,
    const float* __restrict__ Whh,
    const float* __restrict__ fcW, const float* __restrict__ fcb,
    float* __restrict__ out)
{
  __shared__ float h_lds[2][112];
  const int row = blockIdx.x;
  const int l = threadIdx.x;
  const int u0 = l;
  const bool m1 = (l < HIDDEN - 64);
  const int u1 = m1 ? (64 + l) : (HIDDEN - 1);

  float w0[HIDDEN], w1[HIDDEN];
  #pragma unroll
  for (int k = 0; k < HIDDEN; k += 4) {
    const float4 a = *reinterpret_cast<const float4*>(&Whh[u0 * HIDDEN + k]);
    w0[k] = a.x; w0[k+1] = a.y; w0[k+2] = a.z; w0[k+3] = a.w;
    const float4 b = *reinterpret_cast<const float4*>(&Whh[u1 * HIDDEN + k]);
    w1[k] = b.x; w1[k+1] = b.y; w1[k+2] = b.z; w1[k+3] = b.w;
  }
  const float fw0 = fcW[u0];
  const float fw1 = m1 ? fcW[u1] : 0.f;

  h_lds[0][l] = 0.f;
  h_lds[0][l + 48] = 0.f;

  const int* __restrict__ xrow = x + (size_t)row * TSTEPS;
  const int i0 = xrow[0];
  float xp0 = P[i0 * HIDDEN + u0];
  float xp1 = P[i0 * HIDDEN + u1];
  int i_nx = xrow[1];

  float h0 = 0.f, h1 = 0.f;
  for (int t = 0; t < TSTEPS; ++t) {
    const int cur = t & 1, nxt = cur ^ 1;
    const float* __restrict__ Prow = P + i_nx * HIDDEN;
    const float xp0n = Prow[u0];
    const float xp1n = Prow[u1];
    i_nx = (t + 2 < TSTEPS) ? xrow[t + 2] : 0;

    float a0 = xp0, b0 = 0.f, a1v = xp1, b1 = 0.f;
    const float4* __restrict__ hb = reinterpret_cast<const float4*>(&h_lds[cur][0]);
    #pragma unroll
    for (int gq = 0; gq < HIDDEN / 4; ++gq) {
      const float4 hv = hb[gq];
      const int k = 4 * gq;
      if ((gq & 1) == 0) {
        a0  += w0[k]*hv.x + w0[k+1]*hv.y + w0[k+2]*hv.z + w0[k+3]*hv.w;
        a1v += w1[k]*hv.x + w1[k+1]*hv.y + w1[k+2]*hv.z + w1[k+3]*hv.w;
      } else {
        b0 += w0[k]*hv.x + w0[k+1]*hv.y + w0[k+2]*hv.z + w0[k+3]*hv.w;
        b1 += w1[k]*hv.x + w1[k+1]*hv.y + w1[k+2]*hv.z + w1[k+3]*hv.w;
      }
    }
    h0 = fast_tanh(a0 + b0);
    h1 = fast_tanh(a1v + b1);
    h_lds[nxt][u0] = h0;
    if (m1) h_lds[nxt][u1] = h1;
    xp0 = xp0n; xp1 = xp1n;
  }

  float s = h0 * fw0 + (m1 ? h1 * fw1 : 0.f);
  #pragma unroll
  for (int off = 32; off > 0; off >>= 1) s += __shfl_down(s, off);
  if (l == 0) out[row] = 1.0f / (1.0f + __expf(-(s + fcb[0])));
}

// ---------------- host ----------------------------------------------------------
extern "C" void kernel_launch(void* const* d_in, const int* in_sizes, int n_in,
                              void* d_out, int out_size, void* d_ws, size_t ws_size,
                              hipStream_t stream) {
  const int*   x     = (const int*)  d_in[0];
  const float* table = (const float*)d_in[1];
  const float* Wih   = (const float*)d_in[2];
  const float* Whh   = (const float*)d_in[3];
  const float* bih   = (const float*)d_in[4];
  const float* bhh   = (const float*)d_in[5];
  const float* fcW   = (const float*)d_in[6];
  const float* fcb   = (const float*)d_in[7];
  float* out = (float*)d_out;

  unsigned char* ws = (unsigned char*)d_ws;

  if (ws_size >= WS_NEED) {
    unsigned short* WhhHi = (unsigned short*)ws;
    unsigned short* WhhLo = (unsigned short*)(ws + WHH_BYTES);
    float* Pt = (float*)(ws + P_OFF);
    prep_whh<<<(UP * KP + 255) / 256, 256, 0, stream>>>(Whh, WhhHi, WhhLo);
    proj_kernel<<<(VOCAB + 15) / 16, 128, 0, stream>>>(table, Wih, bih, bhh, Pt);
    rnn_mfma_kernel<<<NBLK, 256, 0, stream>>>(x, ws, fcW, fcb, out);
  } else {
    float* Pt = (float*)ws;
    proj_kernel<<<(VOCAB + 15) / 16, 128, 0, stream>>>(table, Wih, bih, bhh, Pt);
    rnn_wave_kernel<<<BATCH, 64, 0, stream>>>(x, Pt, Whh, fcW, fcb, out);
  }
}